// Round 3
// baseline (16421.536 us; speedup 1.0000x reference)
//
#include <hip/hip_runtime.h>
#include <hip/hip_cooperative_groups.h>
#include <math.h>

namespace cg = cooperative_groups;

// Problem constants
#define BB 256      // batch
#define TT 255      // T1
#define NN 128      // input channels
#define HH 256      // hidden

// Workspace layout (floats):
//   E    : [B][N]      @ 0       (32768)   exp(score_x + attn_b)   (constant after init)
//   hbuf : [2][B][H]   @ 32768   (131072)  double-buffered hidden state
//   s3   : [3][B]      @ 163840  (768)     triple-buffered attention scalar s[b]

__device__ __forceinline__ float sigmoidf_(float v) { return 1.0f / (1.0f + __expf(-v)); }

__global__ void __launch_bounds__(256, 1) darnn_persistent(
    const float* __restrict__ x, const float* __restrict__ attn_W,
    const float* __restrict__ attn_b,
    const float* __restrict__ W_ih, const float* __restrict__ W_hh,
    const float* __restrict__ b_ih, const float* __restrict__ b_hh,
    float* __restrict__ ws, float* __restrict__ out_w, float* __restrict__ out_e)
{
    cg::grid_group grid = cg::this_grid();

    // 388-float row pitch: row-to-row bank shift = 388 % 32 = 4 banks, so the 8
    // distinct rows read per wave land on disjoint 4-bank groups (conflict-free b128).
    __shared__ float es_lds[256];
    __shared__ float denp[2][128];
    __shared__ float bias_lds[32];
    __shared__ float A_lds[32][388];       // cols 0..127 = w_in, 128..383 = h
    __shared__ float W_lds[32][388];       // cols 0..127 = W_ih, 128..383 = W_hh (staged ONCE)
    __shared__ float part_lds[4][32][36];  // per-wave K-split partials

    float* E    = ws;
    float* hbuf = ws + 32768;
    float* s3   = ws + 163840;

    const int tid    = threadIdx.x;
    const int bt     = blockIdx.x >> 5;   // 0..7
    const int jt     = blockIdx.x & 31;   // 0..31
    const int bbase  = bt * 32;
    const int hhbase = jt * 8;
    const int gtid   = blockIdx.x * 256 + tid;   // 0..65535 (256 blocks!)

    // ===================== init (once) =====================
    // Stage W_ih rows: 32 j x 128  (row jl <-> global j = (jl>>3)*256 + hhbase + (jl&7))
#pragma unroll
    for (int i = 0; i < 4; ++i) {
        const int tp = i * 256 + tid;
        const int jl = tp >> 5, k4 = tp & 31;
        const int jg = (jl >> 3) * 256 + hhbase + (jl & 7);
        *(float4*)&W_lds[jl][k4 * 4] = *(const float4*)&W_ih[(size_t)jg * NN + k4 * 4];
    }
    // Stage W_hh rows: 32 j x 256
#pragma unroll
    for (int i = 0; i < 8; ++i) {
        const int tp = i * 256 + tid;
        const int jl = tp >> 6, k4 = tp & 63;
        const int jg = (jl >> 3) * 256 + hhbase + (jl & 7);
        *(float4*)&W_lds[jl][128 + k4 * 4] = *(const float4*)&W_hh[(size_t)jg * HH + k4 * 4];
    }
    if (tid < 32) {
        const int jg = (tid >> 3) * 256 + hhbase + (tid & 7);
        bias_lds[tid] = b_ih[jg] + b_hh[jg];
    }
    // Zero both h buffers + all 3 s buffers (ws is poisoned 0xAA each launch).
    // 65536 threads -> each does 2 elements of hbuf.
    for (int i = gtid; i < 131072; i += 65536) hbuf[i] = 0.f;
    if (gtid < 768) s3[gtid] = 0.f;
    // E[b,n] = exp(score_x[b,n] + attn_b)  — ONLY the first 32768 threads (b < 256!)
    if (gtid < 32768) {
        const int b = gtid >> 7, n = gtid & 127;
        const float* Wx = attn_W + 2 * HH;
        const float* xp = x + (size_t)b * TT * NN + n;
        float a0 = 0.f, a1 = 0.f, a2 = 0.f, a3 = 0.f;
        int t = 0;
        for (; t + 4 <= TT; t += 4) {
            a0 += xp[(size_t)(t + 0) * NN] * Wx[t + 0];
            a1 += xp[(size_t)(t + 1) * NN] * Wx[t + 1];
            a2 += xp[(size_t)(t + 2) * NN] * Wx[t + 2];
            a3 += xp[(size_t)(t + 3) * NN] * Wx[t + 3];
        }
        for (; t < TT; ++t) a0 += xp[(size_t)t * NN] * Wx[t];
        E[gtid] = __expf((a0 + a1) + (a2 + a3) + attn_b[0]);
    }
    __threadfence();
    grid.sync();

    // Persistent per-thread LSTM cell state: thread (bl,hhl)=(tid>>3, tid&7) owns (bg5,hg5).
    float c_reg = 0.f;
    const int bg5 = bbase + (tid >> 3);
    const int hg5 = hhbase + (tid & 7);
    const float Wh5 = attn_W[hg5];
    const float Wc5 = attn_W[HH + hg5];

    // ===================== time loop =====================
    for (int t = 0; t < TT; ++t) {
        const float* s_cur = s3 + (size_t)(t % 3) * 256;
        float*       s_nxt = s3 + (size_t)((t + 1) % 3) * 256;
        float*       s_zro = s3 + (size_t)((t + 2) % 3) * 256;
        const float* hin   = hbuf + (size_t)(t & 1) * 65536;
        float*       hout  = hbuf + (size_t)((t + 1) & 1) * 65536;

        // ---- phase 1: es[b] = exp(s[b]); rotate-zero the (t+2) s-buffer
        es_lds[tid] = __expf(s_cur[tid]);
        if (blockIdx.x == 0) s_zro[tid] = 0.f;
        __syncthreads();

        // ---- phase 2: stage h tile; softmax denominator partials
#pragma unroll
        for (int i = 0; i < 8; ++i) {
            const int tp = i * 256 + tid;
            const int bl = tp >> 6, k4 = tp & 63;
            *(float4*)&A_lds[bl][128 + k4 * 4] =
                *(const float4*)&hin[(size_t)(bbase + bl) * HH + k4 * 4];
        }
        {
            const int n = tid & 127, half = tid >> 7;
            const float* Ep = E + (size_t)half * 128 * NN + n;
            float d0 = 0.f, d1 = 0.f, d2 = 0.f, d3 = 0.f;
#pragma unroll 8
            for (int bb = 0; bb < 128; bb += 4) {
                d0 += Ep[(size_t)(bb + 0) * NN] * es_lds[half * 128 + bb + 0];
                d1 += Ep[(size_t)(bb + 1) * NN] * es_lds[half * 128 + bb + 1];
                d2 += Ep[(size_t)(bb + 2) * NN] * es_lds[half * 128 + bb + 2];
                d3 += Ep[(size_t)(bb + 3) * NN] * es_lds[half * 128 + bb + 3];
            }
            denp[half][n] = (d0 + d1) + (d2 + d3);
        }
        __syncthreads();

        // ---- phase 3: w_in = E*es*x/den -> A_lds[:,0:128] and input_weighted output
#pragma unroll
        for (int i = 0; i < 16; ++i) {
            const int tp = i * 256 + tid;
            const int bl = tp >> 7, n = tp & 127;
            const int bg = bbase + bl;
            const float den = denp[0][n] + denp[1][n];
            const float wv = E[(size_t)bg * NN + n] * es_lds[bg] *
                             x[((size_t)bg * TT + t) * NN + n] / den;
            A_lds[bl][n] = wv;
            out_w[((size_t)bg * TT + t) * NN + n] = wv;
        }
        __syncthreads();

        // ---- phase 4: GEMM gates[32b x 32j] = A[32 x 384] * W[32 x 384]^T (per-wave K-split)
        {
            const int w    = tid >> 6;
            const int lane = tid & 63;
            const int bi   = lane & 7;
            const int ji   = lane >> 3;
            float acc[4][4] = {};
            const int k0 = w * 96;
#pragma unroll 2
            for (int kk = 0; kk < 96; kk += 4) {
                float4 av[4], wv4[4];
#pragma unroll
                for (int u = 0; u < 4; ++u) av[u] = *(const float4*)&A_lds[bi + 8 * u][k0 + kk];
#pragma unroll
                for (int v = 0; v < 4; ++v) wv4[v] = *(const float4*)&W_lds[ji + 8 * v][k0 + kk];
#pragma unroll
                for (int u = 0; u < 4; ++u)
#pragma unroll
                    for (int v = 0; v < 4; ++v)
                        acc[u][v] += av[u].x * wv4[v].x + av[u].y * wv4[v].y +
                                     av[u].z * wv4[v].z + av[u].w * wv4[v].w;
            }
#pragma unroll
            for (int u = 0; u < 4; ++u)
#pragma unroll
                for (int v = 0; v < 4; ++v)
                    part_lds[w][bi + 8 * u][ji + 8 * v] = acc[u][v];
        }
        __syncthreads();

        // ---- phase 5: K-combine + bias + LSTM pointwise + outputs + next-step s atomics
        {
            const int bl = tid >> 3, hhl = tid & 7;
            float gate[4];
#pragma unroll
            for (int g = 0; g < 4; ++g) {
                const int jl = g * 8 + hhl;
                const float sum = part_lds[0][bl][jl] + part_lds[1][bl][jl] +
                                  part_lds[2][bl][jl] + part_lds[3][bl][jl];
                gate[g] = sum + bias_lds[jl];
            }
            const float ig = sigmoidf_(gate[0]);
            const float fg = sigmoidf_(gate[1]);
            const float gg = tanhf(gate[2]);
            const float og = sigmoidf_(gate[3]);
            const float cn = fg * c_reg + ig * gg;
            const float hn = og * tanhf(cn);
            c_reg = cn;
            hout[(size_t)bg5 * HH + hg5] = hn;
            out_e[((size_t)bg5 * TT + t) * HH + hg5] = hn;

            float sp = hn * Wh5 + cn * Wc5;
            sp += __shfl_xor(sp, 1);
            sp += __shfl_xor(sp, 2);
            sp += __shfl_xor(sp, 4);
            if (hhl == 0) atomicAdd(&s_nxt[bg5], sp);
        }
        __threadfence();
        grid.sync();
    }
}

extern "C" void kernel_launch(void* const* d_in, const int* in_sizes, int n_in,
                              void* d_out, int out_size, void* d_ws, size_t ws_size,
                              hipStream_t stream)
{
    const float* x      = (const float*)d_in[0];
    const float* attn_W = (const float*)d_in[1];
    const float* attn_b = (const float*)d_in[2];
    const float* W_ih   = (const float*)d_in[3];
    const float* W_hh   = (const float*)d_in[4];
    const float* b_ih   = (const float*)d_in[5];
    const float* b_hh   = (const float*)d_in[6];

    float* ws    = (float*)d_ws;
    float* out_w = (float*)d_out;                 // input_weighted [B][T1][N]
    float* out_e = out_w + (size_t)BB * TT * NN;  // input_encoded  [B][T1][H]

    void* args[] = {(void*)&x, (void*)&attn_W, (void*)&attn_b, (void*)&W_ih,
                    (void*)&W_hh, (void*)&b_ih, (void*)&b_hh,
                    (void*)&ws, (void*)&out_w, (void*)&out_e};
    hipLaunchCooperativeKernel((void*)darnn_persistent, dim3(256), dim3(256),
                               args, 0, stream);
}

// Round 4
// 5772.531 us; speedup vs baseline: 2.8448x; 2.8448x over previous
//
#include <hip/hip_runtime.h>
#include <math.h>

// Problem constants
#define BB 256      // batch
#define TT 255      // T1
#define NN 128      // input channels
#define HH 256      // hidden
#define NBLK 256    // grid blocks (1 per CU)

// Workspace layout (floats):
//   E    : [B][N]   @ 0      (32768)  exp(score_x + attn_b), constant after init
//   s3   : [3][B]   @ 32768  (768)    triple-buffered attention scalar s[b]
//   cnt  : unsigned @ 33536           monotonic epoch barrier counter
//   ready: unsigned @ 33537           init handshake flag
// total 33538 floats = 134,152 B  (prior rounds proved ws_size >= 658 KB)

#define WS_S3   32768
#define WS_CNT  33536
#define WS_RDY  33537
#define RDY_MAGIC 0x5EED5EEDu

__device__ __forceinline__ float sigmoidf_(float v) { return 1.0f / (1.0f + __expf(-v)); }

// Agent-scope (cross-XCD coherent) relaxed load/store: lower to global_load/store with
// sc0 sc1 set -> bypass non-coherent per-XCD L2, hit the device coherence point.
__device__ __forceinline__ float scloadf(const float* p) {
    return __hip_atomic_load(p, __ATOMIC_RELAXED, __HIP_MEMORY_SCOPE_AGENT);
}
__device__ __forceinline__ void scstoref(float* p, float v) {
    __hip_atomic_store(p, v, __ATOMIC_RELAXED, __HIP_MEMORY_SCOPE_AGENT);
}
__device__ __forceinline__ unsigned scloadu(const unsigned* p) {
    return __hip_atomic_load(p, __ATOMIC_RELAXED, __HIP_MEMORY_SCOPE_AGENT);
}
__device__ __forceinline__ void scstoreu(unsigned* p, unsigned v) {
    __hip_atomic_store(p, v, __ATOMIC_RELAXED, __HIP_MEMORY_SCOPE_AGENT);
}

// Monotonic-epoch grid barrier. All communicated data was written with sc atomics,
// so vmcnt(0) (ACK at coherence point) + the counter RMW is a correct release;
// consumers re-read through sc loads, so no cache invalidate is needed.
__device__ __forceinline__ void gbar(unsigned* cnt, unsigned target) {
    asm volatile("s_waitcnt vmcnt(0)" ::: "memory");
    __syncthreads();
    if (threadIdx.x == 0) {
        __hip_atomic_fetch_add(cnt, 1u, __ATOMIC_RELAXED, __HIP_MEMORY_SCOPE_AGENT);
        while (scloadu(cnt) < target) __builtin_amdgcn_s_sleep(8);
    }
    __syncthreads();
}

__global__ void __launch_bounds__(256, 1) darnn_persistent(
    const float* __restrict__ x, const float* __restrict__ attn_W,
    const float* __restrict__ attn_b,
    const float* __restrict__ W_ih, const float* __restrict__ W_hh,
    const float* __restrict__ b_ih, const float* __restrict__ b_hh,
    float* __restrict__ ws, float* __restrict__ out_w, float* __restrict__ out_e)
{
    // 388-float row pitch: row-to-row bank shift = 388 % 32 = 4 banks, so the 8
    // distinct rows read per wave land on disjoint 4-bank groups (conflict-free b128).
    __shared__ float es_lds[256];
    __shared__ float denp[2][128];
    __shared__ float bias_lds[32];
    __shared__ float A_lds[32][388];       // cols 0..127 = w_in, 128..383 = h
    __shared__ float W_lds[32][388];       // cols 0..127 = W_ih, 128..383 = W_hh (staged ONCE)
    __shared__ float part_lds[4][32][36];  // per-wave K-split partials

    float*    E    = ws;
    float*    s3   = ws + WS_S3;
    unsigned* cnt  = (unsigned*)(ws + WS_CNT);
    unsigned* rdy  = (unsigned*)(ws + WS_RDY);

    const int tid    = threadIdx.x;
    const int bt     = blockIdx.x >> 5;   // 0..7
    const int jt     = blockIdx.x & 31;   // 0..31
    const int bbase  = bt * 32;
    const int hhbase = jt * 8;
    const int gtid   = blockIdx.x * 256 + tid;   // 0..65535

    // ===================== init (once) =====================
    // Stage W_ih rows: 32 j x 128  (row jl <-> global j = (jl>>3)*256 + hhbase + (jl&7))
#pragma unroll
    for (int i = 0; i < 4; ++i) {
        const int tp = i * 256 + tid;
        const int jl = tp >> 5, k4 = tp & 31;
        const int jg = (jl >> 3) * 256 + hhbase + (jl & 7);
        *(float4*)&W_lds[jl][k4 * 4] = *(const float4*)&W_ih[(size_t)jg * NN + k4 * 4];
    }
    // Stage W_hh rows: 32 j x 256
#pragma unroll
    for (int i = 0; i < 8; ++i) {
        const int tp = i * 256 + tid;
        const int jl = tp >> 6, k4 = tp & 63;
        const int jg = (jl >> 3) * 256 + hhbase + (jl & 7);
        *(float4*)&W_lds[jl][128 + k4 * 4] = *(const float4*)&W_hh[(size_t)jg * HH + k4 * 4];
    }
    if (tid < 32) {
        const int jg = (tid >> 3) * 256 + hhbase + (tid & 7);
        bias_lds[tid] = b_ih[jg] + b_hh[jg];
    }
    // Zero all 3 s buffers (sc stores: must be visible cross-XCD; ws poisoned 0xAA)
    if (gtid < 768) scstoref(&s3[gtid], 0.f);
    // E[b,n] = exp(score_x[b,n] + attn_b) — first 32768 threads only (b < 256)
    if (gtid < 32768) {
        const int b = gtid >> 7, n = gtid & 127;
        const float* Wx = attn_W + 2 * HH;
        const float* xp = x + (size_t)b * TT * NN + n;
        float a0 = 0.f, a1 = 0.f, a2 = 0.f, a3 = 0.f;
        int t = 0;
        for (; t + 4 <= TT; t += 4) {
            a0 += xp[(size_t)(t + 0) * NN] * Wx[t + 0];
            a1 += xp[(size_t)(t + 1) * NN] * Wx[t + 1];
            a2 += xp[(size_t)(t + 2) * NN] * Wx[t + 2];
            a3 += xp[(size_t)(t + 3) * NN] * Wx[t + 3];
        }
        for (; t < TT; ++t) a0 += xp[(size_t)t * NN] * Wx[t];
        scstoref(&E[gtid], __expf((a0 + a1) + (a2 + a3) + attn_b[0]));
    }
    // Barrier-counter init handshake: block 0 publishes cnt=0 then the magic flag.
    asm volatile("s_waitcnt vmcnt(0)" ::: "memory");
    __syncthreads();
    if (tid == 0) {
        if (blockIdx.x == 0) {
            scstoreu(cnt, 0u);
            asm volatile("s_waitcnt vmcnt(0)" ::: "memory");  // order cnt before flag
            scstoreu(rdy, RDY_MAGIC);
        } else {
            while (scloadu(rdy) != RDY_MAGIC) __builtin_amdgcn_s_sleep(8);
        }
    }
    __syncthreads();
    unsigned tgt = NBLK;
    gbar(cnt, tgt);   // epoch 1: all init writes (E, s3) visible everywhere

    // Persistent per-thread LSTM cell state: thread (bl,hhl)=(tid>>3, tid&7) owns (bg5,hg5).
    float c_reg = 0.f;
    const int bg5 = bbase + (tid >> 3);
    const int hg5 = hhbase + (tid & 7);
    const float Wh5 = attn_W[hg5];
    const float Wc5 = attn_W[HH + hg5];

    // ===================== time loop =====================
    for (int t = 0; t < TT; ++t) {
        const float* s_cur = s3 + (size_t)(t % 3) * 256;
        float*       s_nxt = s3 + (size_t)((t + 1) % 3) * 256;
        float*       s_zro = s3 + (size_t)((t + 2) % 3) * 256;

        // ---- phase 1: es[b] = exp(s[b]); rotate-zero the (t+2) s-buffer
        es_lds[tid] = __expf(scloadf(&s_cur[tid]));
        if (blockIdx.x == 0) scstoref(&s_zro[tid], 0.f);
        __syncthreads();

        // ---- phase 2: stage h tile (from out_e[.., t-1, ..]); softmax denom partials
        if (t > 0) {
#pragma unroll 8
            for (int i = 0; i < 32; ++i)
                A_lds[i][128 + tid] =
                    scloadf(&out_e[((size_t)(bbase + i) * TT + (t - 1)) * HH + tid]);
        } else {
#pragma unroll 8
            for (int i = 0; i < 32; ++i) A_lds[i][128 + tid] = 0.f;
        }
        {
            const int n = tid & 127, half = tid >> 7;
            const float* Ep = E + (size_t)half * 128 * NN + n;
            float d0 = 0.f, d1 = 0.f, d2 = 0.f, d3 = 0.f;
#pragma unroll 8
            for (int bb = 0; bb < 128; bb += 4) {
                d0 += Ep[(size_t)(bb + 0) * NN] * es_lds[half * 128 + bb + 0];
                d1 += Ep[(size_t)(bb + 1) * NN] * es_lds[half * 128 + bb + 1];
                d2 += Ep[(size_t)(bb + 2) * NN] * es_lds[half * 128 + bb + 2];
                d3 += Ep[(size_t)(bb + 3) * NN] * es_lds[half * 128 + bb + 3];
            }
            denp[half][n] = (d0 + d1) + (d2 + d3);
        }
        __syncthreads();

        // ---- phase 3: w_in = E*es*x/den -> A_lds[:,0:128] and input_weighted output
#pragma unroll
        for (int i = 0; i < 16; ++i) {
            const int tp = i * 256 + tid;
            const int bl = tp >> 7, n = tp & 127;
            const int bg = bbase + bl;
            const float den = denp[0][n] + denp[1][n];
            const float wv = E[(size_t)bg * NN + n] * es_lds[bg] *
                             x[((size_t)bg * TT + t) * NN + n] / den;
            A_lds[bl][n] = wv;
            out_w[((size_t)bg * TT + t) * NN + n] = wv;
        }
        __syncthreads();

        // ---- phase 4: GEMM gates[32b x 32j] = A[32 x 384] * W[32 x 384]^T (per-wave K-split)
        {
            const int w    = tid >> 6;
            const int lane = tid & 63;
            const int bi   = lane & 7;
            const int ji   = lane >> 3;
            float acc[4][4] = {};
            const int k0 = w * 96;
#pragma unroll 2
            for (int kk = 0; kk < 96; kk += 4) {
                float4 av[4], wv4[4];
#pragma unroll
                for (int u = 0; u < 4; ++u) av[u] = *(const float4*)&A_lds[bi + 8 * u][k0 + kk];
#pragma unroll
                for (int v = 0; v < 4; ++v) wv4[v] = *(const float4*)&W_lds[ji + 8 * v][k0 + kk];
#pragma unroll
                for (int u = 0; u < 4; ++u)
#pragma unroll
                    for (int v = 0; v < 4; ++v)
                        acc[u][v] += av[u].x * wv4[v].x + av[u].y * wv4[v].y +
                                     av[u].z * wv4[v].z + av[u].w * wv4[v].w;
            }
#pragma unroll
            for (int u = 0; u < 4; ++u)
#pragma unroll
                for (int v = 0; v < 4; ++v)
                    part_lds[w][bi + 8 * u][ji + 8 * v] = acc[u][v];
        }
        __syncthreads();

        // ---- phase 5: K-combine + bias + LSTM pointwise + outputs + next-step s atomics
        {
            const int bl = tid >> 3, hhl = tid & 7;
            float gate[4];
#pragma unroll
            for (int g = 0; g < 4; ++g) {
                const int jl = g * 8 + hhl;
                const float sum = part_lds[0][bl][jl] + part_lds[1][bl][jl] +
                                  part_lds[2][bl][jl] + part_lds[3][bl][jl];
                gate[g] = sum + bias_lds[jl];
            }
            const float ig = sigmoidf_(gate[0]);
            const float fg = sigmoidf_(gate[1]);
            const float gg = tanhf(gate[2]);
            const float og = sigmoidf_(gate[3]);
            const float cn = fg * c_reg + ig * gg;
            const float hn = og * tanhf(cn);
            c_reg = cn;
            // h lives only in out_e; sc store so next step's cross-XCD readers see it
            scstoref(&out_e[((size_t)bg5 * TT + t) * HH + hg5], hn);

            float sp = hn * Wh5 + cn * Wc5;
            sp += __shfl_xor(sp, 1);
            sp += __shfl_xor(sp, 2);
            sp += __shfl_xor(sp, 4);
            if (hhl == 0) atomicAdd(&s_nxt[bg5], sp);
        }

        tgt += NBLK;
        gbar(cnt, tgt);
    }
}

extern "C" void kernel_launch(void* const* d_in, const int* in_sizes, int n_in,
                              void* d_out, int out_size, void* d_ws, size_t ws_size,
                              hipStream_t stream)
{
    const float* x      = (const float*)d_in[0];
    const float* attn_W = (const float*)d_in[1];
    const float* attn_b = (const float*)d_in[2];
    const float* W_ih   = (const float*)d_in[3];
    const float* W_hh   = (const float*)d_in[4];
    const float* b_ih   = (const float*)d_in[5];
    const float* b_hh   = (const float*)d_in[6];

    float* ws    = (float*)d_ws;
    float* out_w = (float*)d_out;                 // input_weighted [B][T1][N]
    float* out_e = out_w + (size_t)BB * TT * NN;  // input_encoded  [B][T1][H]

    void* args[] = {(void*)&x, (void*)&attn_W, (void*)&attn_b, (void*)&W_ih,
                    (void*)&W_hh, (void*)&b_ih, (void*)&b_hh,
                    (void*)&ws, (void*)&out_w, (void*)&out_e};
    hipLaunchCooperativeKernel((void*)darnn_persistent, dim3(NBLK), dim3(256),
                               args, 0, stream);
}

// Round 6
// 4715.743 us; speedup vs baseline: 3.4823x; 1.2241x over previous
//
#include <hip/hip_runtime.h>
#include <math.h>

// Problem constants
#define BB 256      // batch
#define TT 255      // T1
#define NN 128      // input channels
#define HH 256      // hidden
#define NBLK 256    // grid blocks (1 per CU)

// Workspace layout (floats):
//   E     : [B][N]       @ 0      (32768)  exp(score_x + attn_b), constant after init
//   s3    : [3][4][256]  @ 32768  (3072)   triple-buffered, 4-replica attention scalar
//   flags : 256 x 32f    @ 35840  (8192)   per-block epoch flag, one 128B line each
//   rdy   : unsigned     @ 44064           init handshake flag
#define WS_S3    32768
#define WS_FLAGS 35840
#define WS_RDY   44064
#define RDY_MAGIC 0x5EED5EEDu

__device__ __forceinline__ float sigmoidf_(float v) { return 1.0f / (1.0f + __expf(-v)); }

// Agent-scope (cross-XCD coherent) relaxed load/store -> global_load/store sc0 sc1,
// served at the device coherence point (correct regardless of block->XCD mapping).
__device__ __forceinline__ float scloadf(const float* p) {
    return __hip_atomic_load(p, __ATOMIC_RELAXED, __HIP_MEMORY_SCOPE_AGENT);
}
__device__ __forceinline__ void scstoref(float* p, float v) {
    __hip_atomic_store(p, v, __ATOMIC_RELAXED, __HIP_MEMORY_SCOPE_AGENT);
}
__device__ __forceinline__ unsigned scloadu(const unsigned* p) {
    return __hip_atomic_load(p, __ATOMIC_RELAXED, __HIP_MEMORY_SCOPE_AGENT);
}
__device__ __forceinline__ void scstoreu(unsigned* p, unsigned v) {
    __hip_atomic_store(p, v, __ATOMIC_RELAXED, __HIP_MEMORY_SCOPE_AGENT);
}

// Contention-free monotonic-epoch grid barrier:
//   arrive: vmcnt(0) (all my sc stores ACKed at coherence point) -> store flags[bid]=epoch
//   wait:   thread tid polls block tid's flag until >= epoch (256 flags checked in parallel)
__device__ __forceinline__ void gbar(unsigned* flags, unsigned epoch) {
    asm volatile("s_waitcnt vmcnt(0)" ::: "memory");
    __syncthreads();   // every wave of the block has drained its stores
    if (threadIdx.x == 0) scstoreu(&flags[(unsigned)blockIdx.x * 32u], epoch);
    while (scloadu(&flags[(unsigned)threadIdx.x * 32u]) < epoch)
        __builtin_amdgcn_s_sleep(4);
    __syncthreads();
}

__global__ void __launch_bounds__(256, 1) darnn_persistent(
    const float* __restrict__ x, const float* __restrict__ attn_W,
    const float* __restrict__ attn_b,
    const float* __restrict__ W_ih, const float* __restrict__ W_hh,
    const float* __restrict__ b_ih, const float* __restrict__ b_hh,
    float* __restrict__ ws, float* __restrict__ out_w, float* __restrict__ out_e)
{
    // 388-float row pitch: row-to-row bank shift = 388 % 32 = 4 banks, so the 8
    // distinct rows read per wave land on disjoint 4-bank groups (conflict-free b128).
    __shared__ float es_lds[256];
    __shared__ float denp[2][128];
    __shared__ float bias_lds[32];
    __shared__ float A_lds[32][388];       // cols 0..127 = w_in, 128..383 = h
    __shared__ float W_lds[32][388];       // cols 0..127 = W_ih, 128..383 = W_hh (staged ONCE)
    __shared__ float part_lds[4][32][36];  // per-wave K-split partials

    float*    E     = ws;
    float*    s3    = ws + WS_S3;          // [3][4][256]
    unsigned* flags = (unsigned*)(ws + WS_FLAGS);
    unsigned* rdy   = (unsigned*)(ws + WS_RDY);

    const int tid    = threadIdx.x;
    const int bt     = blockIdx.x >> 5;   // 0..7
    const int jt     = blockIdx.x & 31;   // 0..31
    const int bbase  = bt * 32;
    const int hhbase = jt * 8;
    const int gtid   = blockIdx.x * 256 + tid;   // 0..65535

    // ===================== init (once) =====================
    // Stage W_ih rows: 32 j x 128  (row jl <-> global j = (jl>>3)*256 + hhbase + (jl&7))
#pragma unroll
    for (int i = 0; i < 4; ++i) {
        const int tp = i * 256 + tid;
        const int jl = tp >> 5, k4 = tp & 31;
        const int jg = (jl >> 3) * 256 + hhbase + (jl & 7);
        *(float4*)&W_lds[jl][k4 * 4] = *(const float4*)&W_ih[(size_t)jg * NN + k4 * 4];
    }
    // Stage W_hh rows: 32 j x 256
#pragma unroll
    for (int i = 0; i < 8; ++i) {
        const int tp = i * 256 + tid;
        const int jl = tp >> 6, k4 = tp & 63;
        const int jg = (jl >> 3) * 256 + hhbase + (jl & 7);
        *(float4*)&W_lds[jl][128 + k4 * 4] = *(const float4*)&W_hh[(size_t)jg * HH + k4 * 4];
    }
    if (tid < 32) {
        const int jg = (tid >> 3) * 256 + hhbase + (tid & 7);
        bias_lds[tid] = b_ih[jg] + b_hh[jg];
    }
    // Zero all 3x4 s replica buffers (blocks 0..11, one 256-slice each)
    if (blockIdx.x < 12) scstoref(&s3[(size_t)blockIdx.x * 256 + tid], 0.f);
    // E[b,n] = exp(score_x[b,n] + attn_b) — first 32768 threads only (b < 256)
    if (gtid < 32768) {
        const int b = gtid >> 7, n = gtid & 127;
        const float* Wx = attn_W + 2 * HH;
        const float* xp = x + (size_t)b * TT * NN + n;
        float a0 = 0.f, a1 = 0.f, a2 = 0.f, a3 = 0.f;
        int t = 0;
        for (; t + 4 <= TT; t += 4) {
            a0 += xp[(size_t)(t + 0) * NN] * Wx[t + 0];
            a1 += xp[(size_t)(t + 1) * NN] * Wx[t + 1];
            a2 += xp[(size_t)(t + 2) * NN] * Wx[t + 2];
            a3 += xp[(size_t)(t + 3) * NN] * Wx[t + 3];
        }
        for (; t < TT; ++t) a0 += xp[(size_t)t * NN] * Wx[t];
        scstoref(&E[gtid], __expf((a0 + a1) + (a2 + a3) + attn_b[0]));
    }
    // Handshake: block 0 zeroes the (poisoned) flag array, then publishes rdy.
    // Nobody touches their arrival flag before seeing rdy -> no lost-arrival race.
    if (blockIdx.x == 0) {
        scstoreu(&flags[(unsigned)tid * 32u], 0u);
        asm volatile("s_waitcnt vmcnt(0)" ::: "memory");
        __syncthreads();
        if (tid == 0) scstoreu(rdy, RDY_MAGIC);
    } else {
        if (tid == 0)
            while (scloadu(rdy) != RDY_MAGIC) __builtin_amdgcn_s_sleep(8);
        __syncthreads();
    }
    unsigned epoch = 1;
    gbar(flags, epoch);   // all init writes (E, s3) now globally visible

    // Persistent per-thread LSTM cell state: thread (bl,hhl)=(tid>>3, tid&7) owns (bg5,hg5).
    float c_reg = 0.f;
    const int bg5 = bbase + (tid >> 3);
    const int hg5 = hhbase + (tid & 7);
    const float Wh5 = attn_W[hg5];
    const float Wc5 = attn_W[HH + hg5];
    const int rep5  = (jt & 3) * 256;     // this block's s-replica slot

    // ===================== time loop =====================
    for (int t = 0; t < TT; ++t) {
        const float* s_cur = s3 + (size_t)(t % 3) * 1024;
        float*       s_nxt = s3 + (size_t)((t + 1) % 3) * 1024;
        float*       s_zro = s3 + (size_t)((t + 2) % 3) * 1024;

        // ---- phase 0: prefetch this step's x slice (barrier-independent, hides
        // under phases 1-2)
        float xv[16];
#pragma unroll
        for (int i = 0; i < 16; ++i) {
            const int tp = i * 256 + tid;
            const int bl = tp >> 7, n = tp & 127;
            xv[i] = x[((size_t)(bbase + bl) * TT + t) * NN + n];
        }

        // ---- phase 1: es[b] = exp(sum of 4 s-replicas); rotate-zero the (t+2) buffer
        {
            const float sv = scloadf(&s_cur[tid])       + scloadf(&s_cur[256 + tid]) +
                             scloadf(&s_cur[512 + tid]) + scloadf(&s_cur[768 + tid]);
            es_lds[tid] = __expf(sv);
        }
        if (blockIdx.x < 4) scstoref(&s_zro[(size_t)blockIdx.x * 256 + tid], 0.f);
        __syncthreads();

        // ---- phase 2: stage h tile (from out_e[.., t-1, ..]); softmax denom partials
        if (t > 0) {
#pragma unroll 8
            for (int i = 0; i < 32; ++i)
                A_lds[i][128 + tid] =
                    scloadf(&out_e[((size_t)(bbase + i) * TT + (t - 1)) * HH + tid]);
        } else {
#pragma unroll 8
            for (int i = 0; i < 32; ++i) A_lds[i][128 + tid] = 0.f;
        }
        {
            const int n = tid & 127, half = tid >> 7;
            const float* Ep = E + (size_t)half * 128 * NN + n;
            float d0 = 0.f, d1 = 0.f, d2 = 0.f, d3 = 0.f;
#pragma unroll 8
            for (int bb = 0; bb < 128; bb += 4) {
                d0 += Ep[(size_t)(bb + 0) * NN] * es_lds[half * 128 + bb + 0];
                d1 += Ep[(size_t)(bb + 1) * NN] * es_lds[half * 128 + bb + 1];
                d2 += Ep[(size_t)(bb + 2) * NN] * es_lds[half * 128 + bb + 2];
                d3 += Ep[(size_t)(bb + 3) * NN] * es_lds[half * 128 + bb + 3];
            }
            denp[half][n] = (d0 + d1) + (d2 + d3);
        }
        __syncthreads();

        // ---- phase 3: w_in = E*es*xv/den -> A_lds[:,0:128] and input_weighted output
#pragma unroll
        for (int i = 0; i < 16; ++i) {
            const int tp = i * 256 + tid;
            const int bl = tp >> 7, n = tp & 127;
            const int bg = bbase + bl;
            const float den = denp[0][n] + denp[1][n];
            const float wv = E[(size_t)bg * NN + n] * es_lds[bg] * xv[i] / den;
            A_lds[bl][n] = wv;
            out_w[((size_t)bg * TT + t) * NN + n] = wv;
        }
        __syncthreads();

        // ---- phase 4: GEMM gates[32b x 32j] = A[32 x 384] * W[32 x 384]^T (per-wave K-split)
        {
            const int w    = tid >> 6;
            const int lane = tid & 63;
            const int bi   = lane & 7;
            const int ji   = lane >> 3;
            float acc[4][4] = {};
            const int k0 = w * 96;
#pragma unroll 2
            for (int kk = 0; kk < 96; kk += 4) {
                float4 av[4], wv4[4];
#pragma unroll
                for (int u = 0; u < 4; ++u) av[u] = *(const float4*)&A_lds[bi + 8 * u][k0 + kk];
#pragma unroll
                for (int v = 0; v < 4; ++v) wv4[v] = *(const float4*)&W_lds[ji + 8 * v][k0 + kk];
#pragma unroll
                for (int u = 0; u < 4; ++u)
#pragma unroll
                    for (int v = 0; v < 4; ++v)
                        acc[u][v] += av[u].x * wv4[v].x + av[u].y * wv4[v].y +
                                     av[u].z * wv4[v].z + av[u].w * wv4[v].w;
            }
#pragma unroll
            for (int u = 0; u < 4; ++u)
#pragma unroll
                for (int v = 0; v < 4; ++v)
                    part_lds[w][bi + 8 * u][ji + 8 * v] = acc[u][v];
        }
        __syncthreads();

        // ---- phase 5: K-combine + bias + LSTM pointwise + outputs + next-step s atomics
        {
            const int bl = tid >> 3, hhl = tid & 7;
            float gate[4];
#pragma unroll
            for (int g = 0; g < 4; ++g) {
                const int jl = g * 8 + hhl;
                const float sum = part_lds[0][bl][jl] + part_lds[1][bl][jl] +
                                  part_lds[2][bl][jl] + part_lds[3][bl][jl];
                gate[g] = sum + bias_lds[jl];
            }
            const float ig = sigmoidf_(gate[0]);
            const float fg = sigmoidf_(gate[1]);
            const float gg = tanhf(gate[2]);
            const float og = sigmoidf_(gate[3]);
            const float cn = fg * c_reg + ig * gg;
            const float hn = og * tanhf(cn);
            c_reg = cn;
            // h lives only in out_e; sc store so next step's cross-XCD readers see it
            scstoref(&out_e[((size_t)bg5 * TT + t) * HH + hg5], hn);

            float sp = hn * Wh5 + cn * Wc5;
            sp += __shfl_xor(sp, 1);
            sp += __shfl_xor(sp, 2);
            sp += __shfl_xor(sp, 4);
            if (hhl == 0) atomicAdd(&s_nxt[rep5 + bg5], sp);   // 8-way contention max
        }

        ++epoch;
        gbar(flags, epoch);
    }
}

extern "C" void kernel_launch(void* const* d_in, const int* in_sizes, int n_in,
                              void* d_out, int out_size, void* d_ws, size_t ws_size,
                              hipStream_t stream)
{
    const float* x      = (const float*)d_in[0];
    const float* attn_W = (const float*)d_in[1];
    const float* attn_b = (const float*)d_in[2];
    const float* W_ih   = (const float*)d_in[3];
    const float* W_hh   = (const float*)d_in[4];
    const float* b_ih   = (const float*)d_in[5];
    const float* b_hh   = (const float*)d_in[6];

    float* ws    = (float*)d_ws;
    float* out_w = (float*)d_out;                 // input_weighted [B][T1][N]
    float* out_e = out_w + (size_t)BB * TT * NN;  // input_encoded  [B][T1][H]

    void* args[] = {(void*)&x, (void*)&attn_W, (void*)&attn_b, (void*)&W_ih,
                    (void*)&W_hh, (void*)&b_ih, (void*)&b_hh,
                    (void*)&ws, (void*)&out_w, (void*)&out_e};
    hipLaunchCooperativeKernel((void*)darnn_persistent, dim3(NBLK), dim3(256),
                               args, 0, stream);
}

// Round 7
// 3965.923 us; speedup vs baseline: 4.1407x; 1.1891x over previous
//
#include <hip/hip_runtime.h>
#include <math.h>

// Problem constants
#define BB 256      // batch
#define TT 255      // T1
#define NN 128      // input channels
#define HH 256      // hidden
#define NBLK 256    // grid blocks (1 per CU)

// Workspace layout (floats):
//   E     : [B][N]       @ 0      (32768)  exp(score_x + attn_b), constant after init
//   s3    : [3][4][256]  @ 32768  (3072)   triple-buffered, 4-replica attention scalar
//   flags : 256 u32      @ 35840  (256)    packed per-block epoch flags (16 lines)
//   rdy   : unsigned     @ 36096           init handshake flag
#define WS_S3    32768
#define WS_FLAGS 35840
#define WS_RDY   36096
#define RDY_MAGIC 0x5EED5EEDu

__device__ __forceinline__ float sigmoidf_(float v) { return 1.0f / (1.0f + __expf(-v)); }

// Agent-scope (cross-XCD coherent) relaxed load/store -> global_load/store sc0 sc1,
// served at the device coherence point (correct regardless of block->XCD mapping).
__device__ __forceinline__ float scloadf(const float* p) {
    return __hip_atomic_load(p, __ATOMIC_RELAXED, __HIP_MEMORY_SCOPE_AGENT);
}
__device__ __forceinline__ void scstoref(float* p, float v) {
    __hip_atomic_store(p, v, __ATOMIC_RELAXED, __HIP_MEMORY_SCOPE_AGENT);
}
__device__ __forceinline__ unsigned scloadu(const unsigned* p) {
    return __hip_atomic_load(p, __ATOMIC_RELAXED, __HIP_MEMORY_SCOPE_AGENT);
}
__device__ __forceinline__ void scstoreu(unsigned* p, unsigned v) {
    __hip_atomic_store(p, v, __ATOMIC_RELAXED, __HIP_MEMORY_SCOPE_AGENT);
}

// Contention-light monotonic-epoch grid barrier:
//   arrive: vmcnt(0) (all my stores ACKed) -> one sc store flags[bid]=epoch (packed 4B)
//   wait:   wave 0 only; lane l polls flags[l], flags[64+l], flags[128+l], flags[192+l]
//           (4 coalesced line-groups per round, 16 lines total), __all-reduced.
__device__ __forceinline__ void gbar(unsigned* flags, unsigned epoch) {
    asm volatile("s_waitcnt vmcnt(0)" ::: "memory");
    __syncthreads();   // every wave of the block has drained its stores
    if (threadIdx.x == 0) scstoreu(&flags[blockIdx.x], epoch);
    if (threadIdx.x < 64) {
        for (;;) {
            const unsigned f0 = scloadu(&flags[threadIdx.x]);
            const unsigned f1 = scloadu(&flags[threadIdx.x + 64]);
            const unsigned f2 = scloadu(&flags[threadIdx.x + 128]);
            const unsigned f3 = scloadu(&flags[threadIdx.x + 192]);
            if (__all((f0 >= epoch) & (f1 >= epoch) & (f2 >= epoch) & (f3 >= epoch)))
                break;
            __builtin_amdgcn_s_sleep(8);
        }
    }
    __syncthreads();
}

__global__ void __launch_bounds__(256, 1) darnn_persistent(
    const float* __restrict__ x, const float* __restrict__ attn_W,
    const float* __restrict__ attn_b,
    const float* __restrict__ W_ih, const float* __restrict__ W_hh,
    const float* __restrict__ b_ih, const float* __restrict__ b_hh,
    float* __restrict__ ws, float* __restrict__ out_w, float* __restrict__ out_e)
{
    // 388-float row pitch: row-to-row bank shift = 388 % 32 = 4 banks, so the 8
    // distinct rows read per wave land on disjoint 4-bank groups (conflict-free b128).
    __shared__ float es_lds[256];
    __shared__ float denp[2][128];
    __shared__ float bias_lds[32];
    __shared__ float A_lds[32][388];       // cols 0..127 = w_in, 128..383 = h
    __shared__ float W_lds[32][388];       // cols 0..127 = W_ih, 128..383 = W_hh (staged ONCE)
    __shared__ float part_lds[4][32][36];  // per-wave K-split partials

    float*    E     = ws;
    float*    s3    = ws + WS_S3;          // [3][4][256]
    unsigned* flags = (unsigned*)(ws + WS_FLAGS);
    unsigned* rdy   = (unsigned*)(ws + WS_RDY);

    const int tid    = threadIdx.x;
    const int bt     = blockIdx.x >> 5;   // 0..7
    const int jt     = blockIdx.x & 31;   // 0..31
    const int bbase  = bt * 32;
    const int hhbase = jt * 8;
    const int gtid   = blockIdx.x * 256 + tid;   // 0..65535

    // ===================== init (once) =====================
    // Stage W_ih rows: 32 j x 128  (row jl <-> global j = (jl>>3)*256 + hhbase + (jl&7))
#pragma unroll
    for (int i = 0; i < 4; ++i) {
        const int tp = i * 256 + tid;
        const int jl = tp >> 5, k4 = tp & 31;
        const int jg = (jl >> 3) * 256 + hhbase + (jl & 7);
        *(float4*)&W_lds[jl][k4 * 4] = *(const float4*)&W_ih[(size_t)jg * NN + k4 * 4];
    }
    // Stage W_hh rows: 32 j x 256
#pragma unroll
    for (int i = 0; i < 8; ++i) {
        const int tp = i * 256 + tid;
        const int jl = tp >> 6, k4 = tp & 63;
        const int jg = (jl >> 3) * 256 + hhbase + (jl & 7);
        *(float4*)&W_lds[jl][128 + k4 * 4] = *(const float4*)&W_hh[(size_t)jg * HH + k4 * 4];
    }
    if (tid < 32) {
        const int jg = (tid >> 3) * 256 + hhbase + (tid & 7);
        bias_lds[tid] = b_ih[jg] + b_hh[jg];
    }
    // Zero all 3x4 s replica buffers (blocks 0..11, one 256-slice each)
    if (blockIdx.x < 12) scstoref(&s3[(size_t)blockIdx.x * 256 + tid], 0.f);
    // E[b,n] = exp(score_x[b,n] + attn_b) — first 32768 threads only (b < 256)
    if (gtid < 32768) {
        const int b = gtid >> 7, n = gtid & 127;
        const float* Wx = attn_W + 2 * HH;
        const float* xp = x + (size_t)b * TT * NN + n;
        float a0 = 0.f, a1 = 0.f, a2 = 0.f, a3 = 0.f;
        int t = 0;
        for (; t + 4 <= TT; t += 4) {
            a0 += xp[(size_t)(t + 0) * NN] * Wx[t + 0];
            a1 += xp[(size_t)(t + 1) * NN] * Wx[t + 1];
            a2 += xp[(size_t)(t + 2) * NN] * Wx[t + 2];
            a3 += xp[(size_t)(t + 3) * NN] * Wx[t + 3];
        }
        for (; t < TT; ++t) a0 += xp[(size_t)t * NN] * Wx[t];
        scstoref(&E[gtid], __expf((a0 + a1) + (a2 + a3) + attn_b[0]));
    }
    // Handshake: block 0 zeroes the (poisoned) flag array, then publishes rdy.
    // Nobody touches their arrival flag (or polls) before seeing rdy.
    if (blockIdx.x == 0) {
        scstoreu(&flags[tid], 0u);
        asm volatile("s_waitcnt vmcnt(0)" ::: "memory");
        __syncthreads();
        if (tid == 0) scstoreu(rdy, RDY_MAGIC);
    } else {
        if (tid == 0)
            while (scloadu(rdy) != RDY_MAGIC) __builtin_amdgcn_s_sleep(8);
        __syncthreads();
    }
    unsigned epoch = 1;
    gbar(flags, epoch);   // all init writes (E, s3) now globally visible

    // Persistent per-thread LSTM cell state: thread (bl,hhl)=(tid>>3, tid&7) owns (bg5,hg5).
    float c_reg = 0.f;
    const int bg5 = bbase + (tid >> 3);
    const int hg5 = hhbase + (tid & 7);
    const float Wh5 = attn_W[hg5];
    const float Wc5 = attn_W[HH + hg5];
    const int rep5  = (jt & 3) * 256;     // this block's s-replica slot

    // x slice for t=0 (prefetched; subsequent slices prefetched under the GEMM)
    float xv[16];
#pragma unroll
    for (int i = 0; i < 16; ++i) {
        const int tp = i * 256 + tid;
        const int bl = tp >> 7, n = tp & 127;
        xv[i] = x[((size_t)(bbase + bl) * TT + 0) * NN + n];
    }

    // ===================== time loop =====================
    for (int t = 0; t < TT; ++t) {
        const float* s_cur = s3 + (size_t)(t % 3) * 1024;
        float*       s_nxt = s3 + (size_t)((t + 1) % 3) * 1024;
        float*       s_zro = s3 + (size_t)((t + 2) % 3) * 1024;

        // ---- phase 1a: s loads FIRST (they gate the es->den->w_in chain)
        const float sv0 = scloadf(&s_cur[tid]);
        const float sv1 = scloadf(&s_cur[256 + tid]);
        const float sv2 = scloadf(&s_cur[512 + tid]);
        const float sv3 = scloadf(&s_cur[768 + tid]);

        // ---- phase 1b: issue h loads (plain float4 — provably fresh: address
        // written once via sc write-through, never L2-cached before this read)
        float4 hv[8];
        if (t > 0) {
#pragma unroll
            for (int i = 0; i < 8; ++i) {
                const int tp = i * 256 + tid;
                const int bl = tp >> 6, k4 = tp & 63;
                hv[i] = *(const float4*)&out_e[((size_t)(bbase + bl) * TT + (t - 1)) * HH + k4 * 4];
            }
        } else {
#pragma unroll
            for (int i = 0; i < 8; ++i) hv[i] = make_float4(0.f, 0.f, 0.f, 0.f);
        }

        // es[b] = exp(sum of 4 replicas); rotate-zero the (t+2) buffer
        es_lds[tid] = __expf((sv0 + sv1) + (sv2 + sv3));
        if (blockIdx.x < 4) scstoref(&s_zro[(size_t)blockIdx.x * 256 + tid], 0.f);
        __syncthreads();

        // ---- phase 2: softmax denom partials (E from L2; h loads landing meanwhile)
        {
            const int n = tid & 127, half = tid >> 7;
            const float* Ep = E + (size_t)half * 128 * NN + n;
            float d0 = 0.f, d1 = 0.f, d2 = 0.f, d3 = 0.f;
#pragma unroll 8
            for (int bb = 0; bb < 128; bb += 4) {
                d0 += Ep[(size_t)(bb + 0) * NN] * es_lds[half * 128 + bb + 0];
                d1 += Ep[(size_t)(bb + 1) * NN] * es_lds[half * 128 + bb + 1];
                d2 += Ep[(size_t)(bb + 2) * NN] * es_lds[half * 128 + bb + 2];
                d3 += Ep[(size_t)(bb + 3) * NN] * es_lds[half * 128 + bb + 3];
            }
            denp[half][n] = (d0 + d1) + (d2 + d3);
        }
        // stage h tile into LDS (b128 writes, sequential banks)
#pragma unroll
        for (int i = 0; i < 8; ++i) {
            const int tp = i * 256 + tid;
            const int bl = tp >> 6, k4 = tp & 63;
            *(float4*)&A_lds[bl][128 + k4 * 4] = hv[i];
        }
        __syncthreads();

        // ---- phase 3: w_in = E*es*xv/den -> A_lds[:,0:128] and input_weighted output
#pragma unroll
        for (int i = 0; i < 16; ++i) {
            const int tp = i * 256 + tid;
            const int bl = tp >> 7, n = tp & 127;
            const int bg = bbase + bl;
            const float den = denp[0][n] + denp[1][n];
            const float wv = E[(size_t)bg * NN + n] * es_lds[bg] * xv[i] / den;
            A_lds[bl][n] = wv;
            out_w[((size_t)bg * TT + t) * NN + n] = wv;
        }
        __syncthreads();

        // ---- phase 4: prefetch x(t+1) under the GEMM; then
        //      GEMM gates[32b x 32j] = A[32 x 384] * W[32 x 384]^T (per-wave K-split)
        float xv_next[16];
        {
            const int tn = (t + 1 < TT) ? (t + 1) : t;
#pragma unroll
            for (int i = 0; i < 16; ++i) {
                const int tp = i * 256 + tid;
                const int bl = tp >> 7, n = tp & 127;
                xv_next[i] = x[((size_t)(bbase + bl) * TT + tn) * NN + n];
            }
        }
        {
            const int w    = tid >> 6;
            const int lane = tid & 63;
            const int bi   = lane & 7;
            const int ji   = lane >> 3;
            float acc[4][4] = {};
            const int k0 = w * 96;
#pragma unroll 2
            for (int kk = 0; kk < 96; kk += 4) {
                float4 av[4], wv4[4];
#pragma unroll
                for (int u = 0; u < 4; ++u) av[u] = *(const float4*)&A_lds[bi + 8 * u][k0 + kk];
#pragma unroll
                for (int v = 0; v < 4; ++v) wv4[v] = *(const float4*)&W_lds[ji + 8 * v][k0 + kk];
#pragma unroll
                for (int u = 0; u < 4; ++u)
#pragma unroll
                    for (int v = 0; v < 4; ++v)
                        acc[u][v] += av[u].x * wv4[v].x + av[u].y * wv4[v].y +
                                     av[u].z * wv4[v].z + av[u].w * wv4[v].w;
            }
#pragma unroll
            for (int u = 0; u < 4; ++u)
#pragma unroll
                for (int v = 0; v < 4; ++v)
                    part_lds[w][bi + 8 * u][ji + 8 * v] = acc[u][v];
        }
        __syncthreads();

        // ---- phase 5: K-combine + bias + LSTM pointwise + outputs + next-step s atomics
        {
            const int bl = tid >> 3, hhl = tid & 7;
            float gate[4];
#pragma unroll
            for (int g = 0; g < 4; ++g) {
                const int jl = g * 8 + hhl;
                const float sum = part_lds[0][bl][jl] + part_lds[1][bl][jl] +
                                  part_lds[2][bl][jl] + part_lds[3][bl][jl];
                gate[g] = sum + bias_lds[jl];
            }
            const float ig = sigmoidf_(gate[0]);
            const float fg = sigmoidf_(gate[1]);
            const float gg = tanhf(gate[2]);
            const float og = sigmoidf_(gate[3]);
            const float cn = fg * c_reg + ig * gg;
            const float hn = og * tanhf(cn);
            c_reg = cn;
            // h lives only in out_e; sc store (write-through) so next step's plain
            // loads fetch fresh data from the coherence point
            scstoref(&out_e[((size_t)bg5 * TT + t) * HH + hg5], hn);

            float sp = hn * Wh5 + cn * Wc5;
            sp += __shfl_xor(sp, 1);
            sp += __shfl_xor(sp, 2);
            sp += __shfl_xor(sp, 4);
            if (hhl == 0) atomicAdd(&s_nxt[rep5 + bg5], sp);   // 8-way contention max
        }

        ++epoch;
        gbar(flags, epoch);

        // hand prefetched x slice to next iteration
#pragma unroll
        for (int i = 0; i < 16; ++i) xv[i] = xv_next[i];
    }
}

extern "C" void kernel_launch(void* const* d_in, const int* in_sizes, int n_in,
                              void* d_out, int out_size, void* d_ws, size_t ws_size,
                              hipStream_t stream)
{
    const float* x      = (const float*)d_in[0];
    const float* attn_W = (const float*)d_in[1];
    const float* attn_b = (const float*)d_in[2];
    const float* W_ih   = (const float*)d_in[3];
    const float* W_hh   = (const float*)d_in[4];
    const float* b_ih   = (const float*)d_in[5];
    const float* b_hh   = (const float*)d_in[6];

    float* ws    = (float*)d_ws;
    float* out_w = (float*)d_out;                 // input_weighted [B][T1][N]
    float* out_e = out_w + (size_t)BB * TT * NN;  // input_encoded  [B][T1][H]

    void* args[] = {(void*)&x, (void*)&attn_W, (void*)&attn_b, (void*)&W_ih,
                    (void*)&W_hh, (void*)&b_ih, (void*)&b_hh,
                    (void*)&ws, (void*)&out_w, (void*)&out_e};
    hipLaunchCooperativeKernel((void*)darnn_persistent, dim3(NBLK), dim3(256),
                               args, 0, stream);
}